// Round 3
// baseline (472.258 us; speedup 1.0000x reference)
//
#include <hip/hip_runtime.h>
#include <cstdint>

// GAT layer via f16 MFMA. Block = 256 thr = 4 waves; wave h = head h.
// TILE = 64 agents/block, N = 200000 = 3125 * 64 exactly.
// C-layout (16x16 MFMA): col = lane&15, row = (lane>>4)*4 + reg.
// A-frag: row m = lane&15, k = (lane>>4)*8 + j.
// B-frag: col n = lane&15, k = (lane>>4)*8 + j (weights pre-transposed [n][k] f16 in ws).
//
// R3: LDS-staged inputs. R2 post-mortem: occupancy 21->39% bought only -7% time;
// waves ~90% stalled with all pipes idle. Cause: every wave redundantly loaded
// the SAME agent/neighbor rows (4x) with lane-scattered 16B fragment loads
// (~32 cache lines per wave instruction) -> vmem address-path serialization.
// Now: per rt-tile, block stages agent(16x64)+neighbor(64x64) f32 ONCE with
// lane-linear coalesced float4 loads, converts to f16, writes XOR-swizzled LDS
// (T2: idx = row*64 + (col ^ ((row&7)<<3))), MFMA frags come from ds_read_b128.
// Tile rt+1 is prefetched into registers before computing rt (T14 async-stage).
// Also: bias folded into MFMA accumulator init; cndmask dropped (exp(-1e8)
// underflows to exactly +0, so e is already masked) - bit-identical.

typedef _Float16 f16;
typedef f16 f16x8 __attribute__((ext_vector_type(8)));
typedef f16 f16x4 __attribute__((ext_vector_type(4)));
typedef float f32x4 __attribute__((ext_vector_type(4)));

#define MFMA(a, b, c) __builtin_amdgcn_mfma_f32_16x16x32_f16(a, b, c, 0, 0, 0)

// Sum across the 16 lanes of a DPP row (all lanes get the total). VALU pipe.
__device__ __forceinline__ float rowsum16(float x) {
    x += __int_as_float(__builtin_amdgcn_update_dpp(0, __float_as_int(x), 0x128, 0xf, 0xf, true)); // row_ror:8
    x += __int_as_float(__builtin_amdgcn_update_dpp(0, __float_as_int(x), 0x124, 0xf, 0xf, true)); // row_ror:4
    x += __int_as_float(__builtin_amdgcn_update_dpp(0, __float_as_int(x), 0x122, 0xf, 0xf, true)); // row_ror:2
    x += __int_as_float(__builtin_amdgcn_update_dpp(0, __float_as_int(x), 0x121, 0xf, 0xf, true)); // row_ror:1
    return x;
}

// ---- prep: transpose+convert weights to f16 [n][k] in ws ----
// ws layout (f16): Wt_a [128][64] @0, Wt_n @8192, Wt_h @16384, Wt_o [64][128] @24576
__global__ void prep_w(const float* __restrict__ Wa, const float* __restrict__ Wn,
                       const float* __restrict__ Wh, const float* __restrict__ Wo,
                       f16* __restrict__ ws) {
    int i = blockIdx.x * 256 + threadIdx.x;   // 0..32767
    int m = i >> 13;                          // matrix id 0..3
    int j = i & 8191;
    if (m < 3) {
        const float* W = (m == 0) ? Wa : ((m == 1) ? Wn : Wh);
        int n = j >> 6, k = j & 63;           // Wt[n][k] = W[k][n], W is [64][128]
        ws[m * 8192 + j] = (f16)W[k * 128 + n];
    } else {
        int n = j >> 7, k = j & 127;          // Wt_o[n][k] = Wo[k][n], Wo is [128][64]
        ws[24576 + j] = (f16)Wo[k * 64 + n];
    }
}

// swizzled f16 index: row pitch 64, XOR 8-f16 chunks within the row by row&7
__device__ __forceinline__ int swz(int row, int col) {
    return row * 64 + (col ^ ((row & 7) << 3));
}

__global__ __launch_bounds__(256, 4)
void gat_mfma(const float* __restrict__ agent,
              const float* __restrict__ neighbor,
              const int*   __restrict__ nmask,
              const f16*   __restrict__ ws,
              const float* __restrict__ ba, const float* __restrict__ bn,
              const float* __restrict__ bh, const float* __restrict__ bo,
              float* __restrict__ out)
{
    __shared__ float mneg[256];        // -1e8 * mask, [agent][k]
    __shared__ f16   sa[16 * 64];      // agent rt-tile, swizzled
    __shared__ f16   sn[64 * 64];      // neighbor rt-tile, row = k*16 + arow, swizzled
    __shared__ f16   ot[64 * 136];     // O tile f16, pitch 136 (A-frag source for out proj)

    const int tid  = threadIdx.x;
    const int lane = tid & 63;
    const int h    = __builtin_amdgcn_readfirstlane(tid >> 6);
    const int l15  = lane & 15;
    const int q    = lane >> 4;
    const long base = (long)blockIdx.x * 64;

    // stage masks (1 value/thread); visible after first loop-top barrier
    mneg[tid] = -1e8f * (float)nmask[base * 4 + tid];

    // per-lane bias values (col = h*32 + ct*16 + l15)
    const float bav[2] = { ba[h * 32 + l15], ba[h * 32 + 16 + l15] };
    const float bnv[2] = { bn[h * 32 + l15], bn[h * 32 + 16 + l15] };
    const float bhv[2] = { bh[h * 32 + l15], bh[h * 32 + 16 + l15] };
    const float bov    = bo[h * 16 + l15];

    const f16* wsn = ws + 8192;
    const f16* wsh = ws + 16384;
    const f16* wso = ws + 24576;

    // persistent B-fragments for the k-loop (wave h: cols 32h + 16ct + l15)
    f16x8 wn[2][2], wh[2][2];
    #pragma unroll
    for (int ct = 0; ct < 2; ++ct)
        #pragma unroll
        for (int ks = 0; ks < 2; ++ks) {
            int n = h * 32 + ct * 16 + l15;
            wn[ct][ks] = *(const f16x8*)(wsn + n * 64 + ks * 32 + q * 8);
            wh[ct][ks] = *(const f16x8*)(wsh + n * 64 + ks * 32 + q * 8);
        }

    // staging geometry: thread t handles row r = t>>4, 4 floats at col (t&15)*4
    const int sr  = tid >> 4;
    const int sc4 = (tid & 15) * 4;
    const float* agp = agent    + base * 64;      // 64 x 64 block tile
    const float* nbp = neighbor + base * 4 * 64;  // 256 x 64 block tile (row = arow*4+k)

    // prefetch tile rt=0 into registers
    float4 ra = *(const float4*)(agp + tid * 4);
    float4 rn4[4];
    #pragma unroll
    for (int i = 0; i < 4; ++i)
        rn4[i] = *(const float4*)(nbp + i * 1024 + tid * 4);

    // ---- rt-outer: stage -> prefetch rt+1 -> compute ----
    #pragma unroll 1
    for (int rt = 0; rt < 4; ++rt) {
        __syncthreads();   // prior-iter LDS reads done (rt=0: mneg ordering)

        // wa frags for phase A (L2-hot ws, issued early; arrive under staging)
        f16x8 wa[2][2];
        #pragma unroll
        for (int ct = 0; ct < 2; ++ct)
            #pragma unroll
            for (int ks = 0; ks < 2; ++ks)
                wa[ct][ks] = *(const f16x8*)(ws + (h * 32 + ct * 16 + l15) * 64 + ks * 32 + q * 8);

        // cvt + swizzled LDS write of the staged tile
        {
            f16x4 va = { (f16)ra.x, (f16)ra.y, (f16)ra.z, (f16)ra.w };
            *(f16x4*)&sa[swz(sr, sc4)] = va;
            #pragma unroll
            for (int i = 0; i < 4; ++i) {
                int rg = i * 16 + sr;                 // global tile row = arow*4 + k
                int lr = (rg & 3) * 16 + (rg >> 2);   // LDS row = k*16 + arow
                f16x4 v = { (f16)rn4[i].x, (f16)rn4[i].y, (f16)rn4[i].z, (f16)rn4[i].w };
                *(f16x4*)&sn[swz(lr, sc4)] = v;
            }
        }

        // issue next tile's loads; in flight across the compute phase
        {
            int rtn = (rt < 3) ? rt + 1 : 3;
            ra = *(const float4*)(agp + rtn * 1024 + tid * 4);
            #pragma unroll
            for (int i = 0; i < 4; ++i)
                rn4[i] = *(const float4*)(nbp + rtn * 4096 + i * 1024 + tid * 4);
        }

        __syncthreads();   // staged tile visible

        // ---- phase A: P_a = relu(agent @ Wa + ba), bias in acc init ----
        f32x4 p0 = { bav[0], bav[0], bav[0], bav[0] };
        f32x4 p1 = { bav[1], bav[1], bav[1], bav[1] };
        {
            f16x8 a0 = *(const f16x8*)&sa[swz(l15, q * 8)];
            f16x8 a1 = *(const f16x8*)&sa[swz(l15, 32 + q * 8)];
            p0 = MFMA(a0, wa[0][0], p0); p0 = MFMA(a1, wa[0][1], p0);
            p1 = MFMA(a0, wa[1][0], p1); p1 = MFMA(a1, wa[1][1], p1);
            #pragma unroll
            for (int r = 0; r < 4; ++r) {
                p0[r] = fmaxf(p0[r], 0.f);
                p1[r] = fmaxf(p1[r], 0.f);
            }
        }

        // ---- fused k-loop: P_n logits + softmax accum of P_h ----
        f32x4 o0 = {0.f, 0.f, 0.f, 0.f}, o1 = {0.f, 0.f, 0.f, 0.f};
        f32x4 ls = {0.f, 0.f, 0.f, 0.f};
        #pragma unroll
        for (int k = 0; k < 4; ++k) {
            int lr = k * 16 + l15;
            f16x8 a0 = *(const f16x8*)&sn[swz(lr, q * 8)];
            f16x8 a1 = *(const f16x8*)&sn[swz(lr, 32 + q * 8)];
            f32x4 n0 = { bnv[0], bnv[0], bnv[0], bnv[0] };
            f32x4 n1 = { bnv[1], bnv[1], bnv[1], bnv[1] };
            f32x4 h0 = { bhv[0], bhv[0], bhv[0], bhv[0] };
            f32x4 h1 = { bhv[1], bhv[1], bhv[1], bhv[1] };
            n0 = MFMA(a0, wn[0][0], n0); n0 = MFMA(a1, wn[0][1], n0);
            n1 = MFMA(a0, wn[1][0], n1); n1 = MFMA(a1, wn[1][1], n1);
            h0 = MFMA(a0, wh[0][0], h0); h0 = MFMA(a1, wh[0][1], h0);
            h1 = MFMA(a0, wh[1][0], h1); h1 = MFMA(a1, wh[1][1], h1);
            #pragma unroll
            for (int r = 0; r < 4; ++r) {
                n0[r] = fmaxf(n0[r], 0.f);
                n1[r] = fmaxf(n1[r], 0.f);
                h0[r] = fmaxf(h0[r], 0.f);
                h1[r] = fmaxf(h1[r], 0.f);
            }
            #pragma unroll
            for (int r = 0; r < 4; ++r) {
                // partial dot over this lane's col; reduce over 16 cols x 2 ct
                float tp = p0[r] * n0[r] + p1[r] * n1[r];
                float logit = rowsum16(tp);                 // replicated in 16 lanes
                float s = logit + mneg[(rt * 16 + q * 4 + r) * 4 + k];
                float e = __expf(s);                        // masked -> exp(-1e8) = +0 exactly
                ls[r] += e;
                o0[r] += e * h0[r];
                o1[r] += e * h1[r];
            }
        }

        // layout transform: C-layout -> ot (row-major f16)
        #pragma unroll
        for (int r = 0; r < 4; ++r) {
            float inv = 0.25f / (ls[r] + 1e-30f);           // fold mean/4 + softmax denom
            int row = rt * 16 + q * 4 + r;
            ot[row * 136 + h * 32 + l15]      = (f16)(o0[r] * inv);
            ot[row * 136 + h * 32 + 16 + l15] = (f16)(o1[r] * inv);
        }
    }
    __syncthreads();

    // ---- out proj: Y = relu(O @ Wo + bo); wave h -> cols [16h, 16h+16) ----
    f16x8 wof[4];
    #pragma unroll
    for (int ks = 0; ks < 4; ++ks)
        wof[ks] = *(const f16x8*)(wso + (h * 16 + l15) * 128 + ks * 32 + q * 8);
    #pragma unroll
    for (int rt = 0; rt < 4; ++rt) {
        f32x4 y = { bov, bov, bov, bov };
        #pragma unroll
        for (int ks = 0; ks < 4; ++ks) {
            f16x8 of = *(const f16x8*)(ot + (rt * 16 + l15) * 136 + ks * 32 + q * 8);
            y = MFMA(of, wof[ks], y);
        }
        #pragma unroll
        for (int r = 0; r < 4; ++r)
            out[(base + rt * 16 + q * 4 + r) * 64 + h * 16 + l15] = fmaxf(y[r], 0.f);
    }
}

extern "C" void kernel_launch(void* const* d_in, const int* in_sizes, int n_in,
                              void* d_out, int out_size, void* d_ws, size_t ws_size,
                              hipStream_t stream) {
    const float* agent    = (const float*)d_in[0];
    const float* neighbor = (const float*)d_in[1];
    const int*   nmask    = (const int*)d_in[2];
    const float* Wa = (const float*)d_in[3];
    const float* ba = (const float*)d_in[4];
    const float* Wn = (const float*)d_in[5];
    const float* bn = (const float*)d_in[6];
    const float* Wh = (const float*)d_in[7];
    const float* bh = (const float*)d_in[8];
    const float* Wo = (const float*)d_in[9];
    const float* bo = (const float*)d_in[10];
    float* out = (float*)d_out;
    f16* ws = (f16*)d_ws;

    prep_w<<<128, 256, 0, stream>>>(Wa, Wn, Wh, Wo, ws);

    const int n = in_sizes[0] / 64;       // 200000
    const int blocks = n / 64;            // 3125
    gat_mfma<<<blocks, 256, 0, stream>>>(agent, neighbor, nmask, ws,
                                         ba, bn, bh, bo, out);
}

// Round 4
// 350.001 us; speedup vs baseline: 1.3493x; 1.3493x over previous
//
#include <hip/hip_runtime.h>
#include <cstdint>

// GAT layer via f16 MFMA. Block = 256 thr = 4 waves; wave h = head h.
// TILE = 64 agents/block, N = 200000 = 3125 * 64 exactly.
// C-layout (16x16 MFMA): col = lane&15, row = (lane>>4)*4 + reg.
// A-frag: row m = lane&15, k = (lane>>4)*8 + j.
// B-frag: col n = lane&15, k = (lane>>4)*8 + j (weights pre-transposed [n][k] f16 in ws).
//
// R3: LDS-staged inputs (coalesced float4 block staging + XOR-swizzled f16 LDS
// + T14 register prefetch of tile rt+1). Correct, but regressed 186->232us:
// WRITE_SIZE 50->365MB, FETCH 127->440MB = register SPILL traffic. The (256,4)
// 128-VGPR cap couldn't hold prefetch(20) + wn/wh(32) + wa(16) + acc(20) + misc.
// R4: single change - __launch_bounds__(256,3) (~170 VGPR budget). Spills
// vanish; occupancy 3 blocks/CU (= R2's effective level, which R2 proved
// sufficient). Isolates staging-structure vs R2 without spill confound.

typedef _Float16 f16;
typedef f16 f16x8 __attribute__((ext_vector_type(8)));
typedef f16 f16x4 __attribute__((ext_vector_type(4)));
typedef float f32x4 __attribute__((ext_vector_type(4)));

#define MFMA(a, b, c) __builtin_amdgcn_mfma_f32_16x16x32_f16(a, b, c, 0, 0, 0)

// Sum across the 16 lanes of a DPP row (all lanes get the total). VALU pipe.
__device__ __forceinline__ float rowsum16(float x) {
    x += __int_as_float(__builtin_amdgcn_update_dpp(0, __float_as_int(x), 0x128, 0xf, 0xf, true)); // row_ror:8
    x += __int_as_float(__builtin_amdgcn_update_dpp(0, __float_as_int(x), 0x124, 0xf, 0xf, true)); // row_ror:4
    x += __int_as_float(__builtin_amdgcn_update_dpp(0, __float_as_int(x), 0x122, 0xf, 0xf, true)); // row_ror:2
    x += __int_as_float(__builtin_amdgcn_update_dpp(0, __float_as_int(x), 0x121, 0xf, 0xf, true)); // row_ror:1
    return x;
}

// ---- prep: transpose+convert weights to f16 [n][k] in ws ----
// ws layout (f16): Wt_a [128][64] @0, Wt_n @8192, Wt_h @16384, Wt_o [64][128] @24576
__global__ void prep_w(const float* __restrict__ Wa, const float* __restrict__ Wn,
                       const float* __restrict__ Wh, const float* __restrict__ Wo,
                       f16* __restrict__ ws) {
    int i = blockIdx.x * 256 + threadIdx.x;   // 0..32767
    int m = i >> 13;                          // matrix id 0..3
    int j = i & 8191;
    if (m < 3) {
        const float* W = (m == 0) ? Wa : ((m == 1) ? Wn : Wh);
        int n = j >> 6, k = j & 63;           // Wt[n][k] = W[k][n], W is [64][128]
        ws[m * 8192 + j] = (f16)W[k * 128 + n];
    } else {
        int n = j >> 7, k = j & 127;          // Wt_o[n][k] = Wo[k][n], Wo is [128][64]
        ws[24576 + j] = (f16)Wo[k * 64 + n];
    }
}

// swizzled f16 index: row pitch 64, XOR 8-f16 chunks within the row by row&7
__device__ __forceinline__ int swz(int row, int col) {
    return row * 64 + (col ^ ((row & 7) << 3));
}

__global__ __launch_bounds__(256, 3)
void gat_mfma(const float* __restrict__ agent,
              const float* __restrict__ neighbor,
              const int*   __restrict__ nmask,
              const f16*   __restrict__ ws,
              const float* __restrict__ ba, const float* __restrict__ bn,
              const float* __restrict__ bh, const float* __restrict__ bo,
              float* __restrict__ out)
{
    __shared__ float mneg[256];        // -1e8 * mask, [agent][k]
    __shared__ f16   sa[16 * 64];      // agent rt-tile, swizzled
    __shared__ f16   sn[64 * 64];      // neighbor rt-tile, row = k*16 + arow, swizzled
    __shared__ f16   ot[64 * 136];     // O tile f16, pitch 136 (A-frag source for out proj)

    const int tid  = threadIdx.x;
    const int lane = tid & 63;
    const int h    = __builtin_amdgcn_readfirstlane(tid >> 6);
    const int l15  = lane & 15;
    const int q    = lane >> 4;
    const long base = (long)blockIdx.x * 64;

    // stage masks (1 value/thread); visible after first loop-top barrier
    mneg[tid] = -1e8f * (float)nmask[base * 4 + tid];

    // per-lane bias values (col = h*32 + ct*16 + l15)
    const float bav[2] = { ba[h * 32 + l15], ba[h * 32 + 16 + l15] };
    const float bnv[2] = { bn[h * 32 + l15], bn[h * 32 + 16 + l15] };
    const float bhv[2] = { bh[h * 32 + l15], bh[h * 32 + 16 + l15] };
    const float bov    = bo[h * 16 + l15];

    const f16* wsn = ws + 8192;
    const f16* wsh = ws + 16384;
    const f16* wso = ws + 24576;

    // persistent B-fragments for the k-loop (wave h: cols 32h + 16ct + l15)
    f16x8 wn[2][2], wh[2][2];
    #pragma unroll
    for (int ct = 0; ct < 2; ++ct)
        #pragma unroll
        for (int ks = 0; ks < 2; ++ks) {
            int n = h * 32 + ct * 16 + l15;
            wn[ct][ks] = *(const f16x8*)(wsn + n * 64 + ks * 32 + q * 8);
            wh[ct][ks] = *(const f16x8*)(wsh + n * 64 + ks * 32 + q * 8);
        }

    // staging geometry: thread t handles row r = t>>4, 4 floats at col (t&15)*4
    const int sr  = tid >> 4;
    const int sc4 = (tid & 15) * 4;
    const float* agp = agent    + base * 64;      // 64 x 64 block tile
    const float* nbp = neighbor + base * 4 * 64;  // 256 x 64 block tile (row = arow*4+k)

    // prefetch tile rt=0 into registers
    float4 ra = *(const float4*)(agp + tid * 4);
    float4 rn4[4];
    #pragma unroll
    for (int i = 0; i < 4; ++i)
        rn4[i] = *(const float4*)(nbp + i * 1024 + tid * 4);

    // ---- rt-outer: stage -> prefetch rt+1 -> compute ----
    #pragma unroll 1
    for (int rt = 0; rt < 4; ++rt) {
        __syncthreads();   // prior-iter LDS reads done (rt=0: mneg ordering)

        // wa frags for phase A (L2-hot ws, issued early; arrive under staging)
        f16x8 wa[2][2];
        #pragma unroll
        for (int ct = 0; ct < 2; ++ct)
            #pragma unroll
            for (int ks = 0; ks < 2; ++ks)
                wa[ct][ks] = *(const f16x8*)(ws + (h * 32 + ct * 16 + l15) * 64 + ks * 32 + q * 8);

        // cvt + swizzled LDS write of the staged tile
        {
            f16x4 va = { (f16)ra.x, (f16)ra.y, (f16)ra.z, (f16)ra.w };
            *(f16x4*)&sa[swz(sr, sc4)] = va;
            #pragma unroll
            for (int i = 0; i < 4; ++i) {
                int rg = i * 16 + sr;                 // global tile row = arow*4 + k
                int lr = (rg & 3) * 16 + (rg >> 2);   // LDS row = k*16 + arow
                f16x4 v = { (f16)rn4[i].x, (f16)rn4[i].y, (f16)rn4[i].z, (f16)rn4[i].w };
                *(f16x4*)&sn[swz(lr, sc4)] = v;
            }
        }

        // issue next tile's loads; in flight across the compute phase
        {
            int rtn = (rt < 3) ? rt + 1 : 3;
            ra = *(const float4*)(agp + rtn * 1024 + tid * 4);
            #pragma unroll
            for (int i = 0; i < 4; ++i)
                rn4[i] = *(const float4*)(nbp + rtn * 4096 + i * 1024 + tid * 4);
        }

        __syncthreads();   // staged tile visible

        // ---- phase A: P_a = relu(agent @ Wa + ba), bias in acc init ----
        f32x4 p0 = { bav[0], bav[0], bav[0], bav[0] };
        f32x4 p1 = { bav[1], bav[1], bav[1], bav[1] };
        {
            f16x8 a0 = *(const f16x8*)&sa[swz(l15, q * 8)];
            f16x8 a1 = *(const f16x8*)&sa[swz(l15, 32 + q * 8)];
            p0 = MFMA(a0, wa[0][0], p0); p0 = MFMA(a1, wa[0][1], p0);
            p1 = MFMA(a0, wa[1][0], p1); p1 = MFMA(a1, wa[1][1], p1);
            #pragma unroll
            for (int r = 0; r < 4; ++r) {
                p0[r] = fmaxf(p0[r], 0.f);
                p1[r] = fmaxf(p1[r], 0.f);
            }
        }

        // ---- fused k-loop: P_n logits + softmax accum of P_h ----
        f32x4 o0 = {0.f, 0.f, 0.f, 0.f}, o1 = {0.f, 0.f, 0.f, 0.f};
        f32x4 ls = {0.f, 0.f, 0.f, 0.f};
        #pragma unroll
        for (int k = 0; k < 4; ++k) {
            int lr = k * 16 + l15;
            f16x8 a0 = *(const f16x8*)&sn[swz(lr, q * 8)];
            f16x8 a1 = *(const f16x8*)&sn[swz(lr, 32 + q * 8)];
            f32x4 n0 = { bnv[0], bnv[0], bnv[0], bnv[0] };
            f32x4 n1 = { bnv[1], bnv[1], bnv[1], bnv[1] };
            f32x4 h0 = { bhv[0], bhv[0], bhv[0], bhv[0] };
            f32x4 h1 = { bhv[1], bhv[1], bhv[1], bhv[1] };
            n0 = MFMA(a0, wn[0][0], n0); n0 = MFMA(a1, wn[0][1], n0);
            n1 = MFMA(a0, wn[1][0], n1); n1 = MFMA(a1, wn[1][1], n1);
            h0 = MFMA(a0, wh[0][0], h0); h0 = MFMA(a1, wh[0][1], h0);
            h1 = MFMA(a0, wh[1][0], h1); h1 = MFMA(a1, wh[1][1], h1);
            #pragma unroll
            for (int r = 0; r < 4; ++r) {
                n0[r] = fmaxf(n0[r], 0.f);
                n1[r] = fmaxf(n1[r], 0.f);
                h0[r] = fmaxf(h0[r], 0.f);
                h1[r] = fmaxf(h1[r], 0.f);
            }
            #pragma unroll
            for (int r = 0; r < 4; ++r) {
                // partial dot over this lane's col; reduce over 16 cols x 2 ct
                float tp = p0[r] * n0[r] + p1[r] * n1[r];
                float logit = rowsum16(tp);                 // replicated in 16 lanes
                float s = logit + mneg[(rt * 16 + q * 4 + r) * 4 + k];
                float e = __expf(s);                        // masked -> exp(-1e8) = +0 exactly
                ls[r] += e;
                o0[r] += e * h0[r];
                o1[r] += e * h1[r];
            }
        }

        // layout transform: C-layout -> ot (row-major f16)
        #pragma unroll
        for (int r = 0; r < 4; ++r) {
            float inv = 0.25f / (ls[r] + 1e-30f);           // fold mean/4 + softmax denom
            int row = rt * 16 + q * 4 + r;
            ot[row * 136 + h * 32 + l15]      = (f16)(o0[r] * inv);
            ot[row * 136 + h * 32 + 16 + l15] = (f16)(o1[r] * inv);
        }
    }
    __syncthreads();

    // ---- out proj: Y = relu(O @ Wo + bo); wave h -> cols [16h, 16h+16) ----
    f16x8 wof[4];
    #pragma unroll
    for (int ks = 0; ks < 4; ++ks)
        wof[ks] = *(const f16x8*)(wso + (h * 16 + l15) * 128 + ks * 32 + q * 8);
    #pragma unroll
    for (int rt = 0; rt < 4; ++rt) {
        f32x4 y = { bov, bov, bov, bov };
        #pragma unroll
        for (int ks = 0; ks < 4; ++ks) {
            f16x8 of = *(const f16x8*)(ot + (rt * 16 + l15) * 136 + ks * 32 + q * 8);
            y = MFMA(of, wof[ks], y);
        }
        #pragma unroll
        for (int r = 0; r < 4; ++r)
            out[(base + rt * 16 + q * 4 + r) * 64 + h * 16 + l15] = fmaxf(y[r], 0.f);
    }
}

extern "C" void kernel_launch(void* const* d_in, const int* in_sizes, int n_in,
                              void* d_out, int out_size, void* d_ws, size_t ws_size,
                              hipStream_t stream) {
    const float* agent    = (const float*)d_in[0];
    const float* neighbor = (const float*)d_in[1];
    const int*   nmask    = (const int*)d_in[2];
    const float* Wa = (const float*)d_in[3];
    const float* ba = (const float*)d_in[4];
    const float* Wn = (const float*)d_in[5];
    const float* bn = (const float*)d_in[6];
    const float* Wh = (const float*)d_in[7];
    const float* bh = (const float*)d_in[8];
    const float* Wo = (const float*)d_in[9];
    const float* bo = (const float*)d_in[10];
    float* out = (float*)d_out;
    f16* ws = (f16*)d_ws;

    prep_w<<<128, 256, 0, stream>>>(Wa, Wn, Wh, Wo, ws);

    const int n = in_sizes[0] / 64;       // 200000
    const int blocks = n / 64;            // 3125
    gat_mfma<<<blocks, 256, 0, stream>>>(agent, neighbor, nmask, ws,
                                         ba, bn, bh, bo, out);
}